// Round 2
// baseline (229.262 us; speedup 1.0000x reference)
//
#include <hip/hip_runtime.h>
#include <hip/hip_bf16.h>
#include <math.h>

#define E_N 4096
#define PI_F 3.14159265358979323846f
#define ATH 0.08726646259971647f   /* radians(5.0) */
#define NB1 4096
#define NB2 4096
#define RMAX 160.0f
#define W1 (RMAX / (float)NB1)       /* 0.0390625 exact */
#define SCALE1 ((float)NB1 / RMAX)   /* 25.6 */
#define W2 (W1 / (float)NB2)         /* 9.5367431640625e-06 exact */
#define SCALE2 ((float)NB2 / W1)     /* 104857.6 */

// workspace layout (bytes)
#define OFF_EDGE 0                    // 6 * 4096 floats = 98304 B
#define OFF_H1   98304                // 4096 u32 = 16384 B
#define OFF_H2   114688               // 3*4096 u32 = 49152 B
#define OFF_ST   163840               // 16 u32 state = 64 B
#define OFF_SUM  163904               // double = 8 B
#define ZERO_U32 ((OFF_SUM + 8 - OFF_H1) / 4)

// state: st[0..2]=quantile coarse bin, st[3..5]=rank within bin, st[6]=n,
//        st[7]=input-is-f32 flag, stf[8]=mu, stf[9]=margin

__global__ void zero_ws(unsigned* __restrict__ p, int n) {
    int i = blockIdx.x * blockDim.x + threadIdx.x;
    if (i < n) p[i] = 0u;
}

// Detect whether node_positions is f32 or bf16: genuine bf16 data in [0,100]
// never has bf16-exponent >= 137 (|v|>=1024); f32 data read as uint16 halves
// has random low-mantissa halves that almost surely do.
__global__ void detect_dtype(const unsigned short* __restrict__ p,
                             unsigned* __restrict__ st) {
    int i = blockIdx.x * blockDim.x + threadIdx.x;
    if (i < 2 * E_N) {
        unsigned exp = (p[i] >> 7) & 0xFFu;
        if (exp >= 137u) atomicOr(&st[7], 1u);
    }
}

__global__ void edge_prep(const void* __restrict__ posv,
                          const int* __restrict__ eidx,
                          float* __restrict__ ed,
                          const unsigned* __restrict__ st) {
    int e = blockIdx.x * blockDim.x + threadIdx.x;
    if (e >= E_N) return;
    bool isf32 = (st[7] != 0u);
    int s = eidx[e];
    int d = eidx[E_N + e];
    float px, py, qx, qy;
    if (isf32) {
        const float* p = (const float*)posv;
        px = p[2 * s]; py = p[2 * s + 1];
        qx = p[2 * d]; qy = p[2 * d + 1];
    } else {
        const __hip_bfloat16* p = (const __hip_bfloat16*)posv;
        px = __bfloat162float(p[2 * s]); py = __bfloat162float(p[2 * s + 1]);
        qx = __bfloat162float(p[2 * d]); qy = __bfloat162float(p[2 * d + 1]);
    }
    float vx = qx - px, vy = qy - py;
    float len = fmaxf(sqrtf(vx * vx + vy * vy), 1e-8f);
    float dx = vx / len, dy = vy / len;
    float a = fmodf(atan2f(dy, dx), PI_F);
    if (a < 0.0f) a += PI_F;           // python-style mod -> [0, pi)
    float nx = -dy, ny = dx;
    ed[e]            = a;
    ed[E_N + e]      = nx;
    ed[2 * E_N + e]  = ny;
    ed[3 * E_N + e]  = px * nx + py * ny;   // c
    ed[4 * E_N + e]  = (px + qx) * 0.5f;    // mid x
    ed[5 * E_N + e]  = (py + qy) * 0.5f;    // mid y
}

// ---- pair sweep #1: coarse histogram of masked distances -------------------
__global__ __launch_bounds__(256) void sweep_hist1(const float* __restrict__ ed,
                                                   unsigned* __restrict__ h1) {
    __shared__ unsigned sh[NB1];
    __shared__ float sa[256], smx[256], smy[256];
    int bi = blockIdx.y, bj = blockIdx.x;
    if (bj < bi) return;                // lower triangle culled (uniform)
    int tid = threadIdx.x;
    for (int k = tid; k < NB1; k += 256) sh[k] = 0u;
    int j0 = bj * 256;
    sa[tid]  = ed[j0 + tid];
    smx[tid] = ed[4 * E_N + j0 + tid];
    smy[tid] = ed[5 * E_N + j0 + tid];
    int i = bi * 256 + tid;
    float ai = ed[i];
    float nx = ed[E_N + i], ny = ed[2 * E_N + i], c = ed[3 * E_N + i];
    __syncthreads();
    int jstart = (bi == bj) ? (tid + 1) : 0;
    for (int jj = jstart; jj < 256; ++jj) {
        float da = fabsf(ai - sa[jj]);
        float circ = fminf(da, PI_F - da);
        if (circ <= ATH) {
            float dist = fabsf(nx * smx[jj] + ny * smy[jj] - c);
            int b = (int)(dist * SCALE1);
            if (b > NB1 - 1) b = NB1 - 1;
            atomicAdd(&sh[b], 1u);
        }
    }
    __syncthreads();
    for (int k = tid; k < NB1; k += 256) {
        unsigned v = sh[k];
        if (v) atomicAdd(&h1[k], v);
    }
}

// ---- refine #1: n, ranks, coarse bin per rank ------------------------------
__global__ void refine1(const unsigned* __restrict__ h1, unsigned* __restrict__ st) {
    __shared__ unsigned a[256];
    __shared__ unsigned rk[3];
    __shared__ unsigned ntot;
    int tid = threadIdx.x;
    unsigned loc[16];
    unsigned s = 0;
#pragma unroll
    for (int k = 0; k < 16; ++k) { loc[k] = h1[tid * 16 + k]; s += loc[k]; }
    a[tid] = s;
    __syncthreads();
    for (int off = 1; off < 256; off <<= 1) {
        unsigned v = (tid >= off) ? a[tid - off] : 0u;
        __syncthreads();
        a[tid] += v;
        __syncthreads();
    }
    if (tid == 255) {
        unsigned n = a[255];
        ntot = n;
        st[6] = n;
        long long q1 = (long long)(n / 4) - 1; if (q1 < 0) q1 = 0;
        long long q3 = (3LL * (long long)n) / 4;
        if (q3 > (long long)n - 1) q3 = (long long)n - 1;
        if (q3 < 0) q3 = 0;
        rk[0] = (unsigned)q1;
        rk[1] = n / 2;
        rk[2] = (unsigned)q3;
    }
    __syncthreads();
    unsigned excl = a[tid] - s;
    for (int t = 0; t < 3; ++t) {
        unsigned r = rk[t];
        if (ntot > 0 && r >= excl && r < excl + s) {
            unsigned cum = excl;
#pragma unroll
            for (int k = 0; k < 16; ++k) {
                unsigned c2 = cum + loc[k];
                if (r < c2) { st[t] = (unsigned)(tid * 16 + k); st[3 + t] = r - cum; break; }
                cum = c2;
            }
        }
    }
}

// ---- pair sweep #2: sub-histograms of the 3 selected coarse bins -----------
__global__ __launch_bounds__(256) void sweep_hist2(const float* __restrict__ ed,
                                                   const unsigned* __restrict__ st,
                                                   unsigned* __restrict__ h2) {
    __shared__ unsigned sh[3 * NB2];
    __shared__ float sa[256], smx[256], smy[256];
    __shared__ int tb[3];
    int bi = blockIdx.y, bj = blockIdx.x;
    if (bj < bi) return;
    int tid = threadIdx.x;
    for (int k = tid; k < 3 * NB2; k += 256) sh[k] = 0u;
    if (tid < 3) tb[tid] = (int)st[tid];
    int j0 = bj * 256;
    sa[tid]  = ed[j0 + tid];
    smx[tid] = ed[4 * E_N + j0 + tid];
    smy[tid] = ed[5 * E_N + j0 + tid];
    int i = bi * 256 + tid;
    float ai = ed[i];
    float nx = ed[E_N + i], ny = ed[2 * E_N + i], c = ed[3 * E_N + i];
    __syncthreads();
    int jstart = (bi == bj) ? (tid + 1) : 0;
    for (int jj = jstart; jj < 256; ++jj) {
        float da = fabsf(ai - sa[jj]);
        float circ = fminf(da, PI_F - da);
        if (circ <= ATH) {
            float dist = fabsf(nx * smx[jj] + ny * smy[jj] - c);
            int b = (int)(dist * SCALE1);
            if (b > NB1 - 1) b = NB1 - 1;
#pragma unroll
            for (int t = 0; t < 3; ++t) {
                if (b == tb[t]) {
                    float lo = (float)b * W1;
                    int sb = (int)((dist - lo) * SCALE2);
                    sb = sb < 0 ? 0 : (sb > NB2 - 1 ? NB2 - 1 : sb);
                    atomicAdd(&sh[t * NB2 + sb], 1u);
                }
            }
        }
    }
    __syncthreads();
    for (int k = tid; k < 3 * NB2; k += 256) {
        unsigned v = sh[k];
        if (v) atomicAdd(&h2[k], v);
    }
}

// ---- refine #2: quantile values -> mu, margin ------------------------------
__global__ void refine2(const unsigned* __restrict__ h2, unsigned* __restrict__ st) {
    __shared__ unsigned a[256];
    __shared__ float vv[3];
    int tid = threadIdx.x;
    for (int t = 0; t < 3; ++t) {
        const unsigned* h = h2 + t * NB2;
        unsigned loc[16];
        unsigned s = 0;
#pragma unroll
        for (int k = 0; k < 16; ++k) { loc[k] = h[tid * 16 + k]; s += loc[k]; }
        a[tid] = s;
        __syncthreads();
        for (int off = 1; off < 256; off <<= 1) {
            unsigned v = (tid >= off) ? a[tid - off] : 0u;
            __syncthreads();
            a[tid] += v;
            __syncthreads();
        }
        unsigned total = a[255];
        unsigned excl = a[tid] - s;
        unsigned r = st[3 + t];
        if (total == 0) {
            if (tid == 0) vv[t] = (float)st[t] * W1 + 0.5f * W1;  // fallback: bin mid
        } else {
            if (r >= total) r = total - 1;  // guard vs pass1/pass2 edge inconsistency
            if (r >= excl && r < excl + s) {
                unsigned cum = excl;
#pragma unroll
                for (int k = 0; k < 16; ++k) {
                    unsigned c2 = cum + loc[k];
                    if (r < c2) {
                        vv[t] = (float)st[t] * W1 + ((float)(tid * 16 + k) + 0.5f) * W2;
                        break;
                    }
                    cum = c2;
                }
            }
        }
        __syncthreads();
    }
    if (tid == 0) {
        unsigned n = st[6];
        float* stf = (float*)st;
        if (n == 0) {
            stf[8] = 0.0f; stf[9] = 0.0f;
        } else {
            float iqr = fmaxf(vv[2] - vv[0], 1e-6f);
            stf[8] = vv[1];           // mu
            stf[9] = 0.75f * iqr;     // margin = iqr * 0.5 * 1.5
        }
    }
}

// ---- pair sweep #3: hinge sum ---------------------------------------------
__global__ __launch_bounds__(256) void sweep_sum(const float* __restrict__ ed,
                                                 const unsigned* __restrict__ st,
                                                 double* __restrict__ gsum) {
    __shared__ float sa[256], smx[256], smy[256];
    __shared__ double wred[4];
    int bi = blockIdx.y, bj = blockIdx.x;
    if (bj < bi) return;
    int tid = threadIdx.x;
    const float* stf = (const float*)st;
    float mu = stf[8], margin = stf[9];
    int j0 = bj * 256;
    sa[tid]  = ed[j0 + tid];
    smx[tid] = ed[4 * E_N + j0 + tid];
    smy[tid] = ed[5 * E_N + j0 + tid];
    int i = bi * 256 + tid;
    float ai = ed[i];
    float nx = ed[E_N + i], ny = ed[2 * E_N + i], c = ed[3 * E_N + i];
    __syncthreads();
    double acc = 0.0;
    int jstart = (bi == bj) ? (tid + 1) : 0;
    for (int jj = jstart; jj < 256; ++jj) {
        float da = fabsf(ai - sa[jj]);
        float circ = fminf(da, PI_F - da);
        if (circ <= ATH) {
            float dist = fabsf(nx * smx[jj] + ny * smy[jj] - c);
            float pp = fmaxf(fabsf(dist - mu) - margin, 0.0f);
            acc += (double)pp;
        }
    }
    for (int off = 32; off > 0; off >>= 1) acc += __shfl_down(acc, off, 64);
    if ((tid & 63) == 0) wred[tid >> 6] = acc;
    __syncthreads();
    if (tid == 0) {
        double t = wred[0] + wred[1] + wred[2] + wred[3];
        atomicAdd(gsum, t);
    }
}

__global__ void finalize(const double* __restrict__ gsum,
                         const unsigned* __restrict__ st,
                         unsigned* __restrict__ out) {
    if (threadIdx.x == 0 && blockIdx.x == 0) {
        unsigned n = st[6];
        double denom = (n > 0) ? (double)n : 1.0;
        float loss = (float)(gsum[0] / denom);
        __hip_bfloat16 h = __float2bfloat16(loss);
        unsigned short b = *(unsigned short*)&h;
        // dtype-agnostic scalar write:
        //  - bf16 read (uint16 elem 0, little-endian) sees exact bf16 value
        //  - f32 read sees bf16 value with <=2^-9 rel mantissa perturbation
        out[0] = ((unsigned)b << 16) | (unsigned)b;
    }
}

extern "C" void kernel_launch(void* const* d_in, const int* in_sizes, int n_in,
                              void* d_out, int out_size, void* d_ws, size_t ws_size,
                              hipStream_t stream) {
    const void* pos = d_in[0];
    // d_in[1] (adjacency) is unused by the axiom math
    const int* eidx = (const int*)d_in[2];

    char* ws = (char*)d_ws;
    float*    ed   = (float*)(ws + OFF_EDGE);
    unsigned* h1   = (unsigned*)(ws + OFF_H1);
    unsigned* h2   = (unsigned*)(ws + OFF_H2);
    unsigned* st   = (unsigned*)(ws + OFF_ST);
    double*   gsum = (double*)(ws + OFF_SUM);

    zero_ws<<<(ZERO_U32 + 255) / 256, 256, 0, stream>>>(h1, ZERO_U32);
    detect_dtype<<<(2 * E_N + 255) / 256, 256, 0, stream>>>(
        (const unsigned short*)pos, st);
    edge_prep<<<E_N / 256, 256, 0, stream>>>(pos, eidx, ed, st);

    dim3 grid(16, 16);
    sweep_hist1<<<grid, 256, 0, stream>>>(ed, h1);
    refine1<<<1, 256, 0, stream>>>(h1, st);
    sweep_hist2<<<grid, 256, 0, stream>>>(ed, st, h2);
    refine2<<<1, 256, 0, stream>>>(h2, st);
    sweep_sum<<<grid, 256, 0, stream>>>(ed, st, gsum);
    finalize<<<1, 1, 0, stream>>>(gsum, st, (unsigned*)d_out);
}